// Round 5
// baseline (283.141 us; speedup 1.0000x reference)
//
#include <hip/hip_runtime.h>
#include <hip/hip_bf16.h>
#include <cstdint>
#include <cstddef>

// Problem constants (fixed by the reference)
#define BATCH 128
#define SEQ   512
#define DIM   1024
#define MROWS (BATCH * SEQ)          // 65536

typedef short short8 __attribute__((ext_vector_type(8)));
typedef __bf16 bf16x8 __attribute__((ext_vector_type(8)));
typedef float f32x4 __attribute__((ext_vector_type(4)));

// ---------- MFMA wrapper: accept either builtin signature (short8 or bf16x8) ----------
template <typename VA> struct other_frag { using type = bf16x8; };
template <> struct other_frag<bf16x8> { using type = short8; };

template <typename VA>
__device__ __forceinline__ auto try_mfma(VA a, VA b, f32x4 c, int)
    -> decltype(__builtin_amdgcn_mfma_f32_16x16x32_bf16(a, b, c, 0, 0, 0)) {
  return __builtin_amdgcn_mfma_f32_16x16x32_bf16(a, b, c, 0, 0, 0);
}
template <typename VA>
__device__ __forceinline__ f32x4 try_mfma(VA a, VA b, f32x4 c, long) {
  using O = typename other_frag<VA>::type;
  O a2 = __builtin_bit_cast(O, a);
  O b2 = __builtin_bit_cast(O, b);
  return __builtin_amdgcn_mfma_f32_16x16x32_bf16(a2, b2, c, 0, 0, 0);
}
__device__ __forceinline__ f32x4 mfma_bf16(short8 a, short8 b, f32x4 c) {
  return try_mfma(a, b, c, 0);
}

// ---------- helpers ----------
__device__ __forceinline__ unsigned short f32_to_bf16(float f) {
  union { float f; uint32_t u; } v; v.f = f;
  uint32_t u = v.u;
  u += 0x7FFFu + ((u >> 16) & 1u);   // round-to-nearest-even
  return (unsigned short)(u >> 16);
}

// 8 x f32 -> 8 x bf16 (RNE); scalar casts, compiler lowers to v_cvt_pk_bf16_f32
__device__ __forceinline__ short8 cvt8(f32x4 a, f32x4 b) {
  bf16x8 o;
  o[0] = (__bf16)a[0]; o[1] = (__bf16)a[1]; o[2] = (__bf16)a[2]; o[3] = (__bf16)a[3];
  o[4] = (__bf16)b[0]; o[5] = (__bf16)b[1]; o[6] = (__bf16)b[2]; o[7] = (__bf16)b[3];
  return __builtin_bit_cast(short8, o);
}

__device__ __forceinline__ void gload_lds16(const void* g, void* l) {
  __builtin_amdgcn_global_load_lds(
      (__attribute__((address_space(1))) void*)g,
      (__attribute__((address_space(3))) void*)l,
      16, 0, 0);
}

__device__ __forceinline__ float fast_tanh(float x) {
  x = fminf(fmaxf(x, -15.0f), 15.0f);
  float e = __expf(2.0f * x);
  return (e - 1.0f) / (e + 1.0f);
}

// ---------- kernel 1: W1 (D x D) -> W1t bf16 (transposed, [e][d]) ----------
__global__ __launch_bounds__(256) void w1t_kernel(const float* __restrict__ W1,
                                                  unsigned short* __restrict__ W1t) {
  __shared__ float tile[64][65];
  int bx = blockIdx.x & 15;    // e-tile
  int by = blockIdx.x >> 4;    // d-tile
  int t = threadIdx.x;
  int c = t & 63, r0 = t >> 6;
#pragma unroll
  for (int i = 0; i < 16; i++) {
    int r = i * 4 + r0;
    tile[r][c] = W1[(size_t)(by * 64 + r) * DIM + bx * 64 + c];
  }
  __syncthreads();
#pragma unroll
  for (int i = 0; i < 16; i++) {
    int r = i * 4 + r0;
    W1t[(size_t)(bx * 64 + r) * DIM + by * 64 + c] = f32_to_bf16(tile[c][r]);
  }
}

// ---------- kernel 2: fused GEMM (fp32 A direct) + tanh + w2-dot -> scores ----------
// C[m][e] = sum_d bf16(X[m][d]) * W1t[e][d]; scores[m] += sum_e tanh(C+b1[e])*w2[e]
//
// m97 structure: 128x128 tile, BK=32, 4 waves (2x2, wave-tile 64x64),
// single-buffered LDS, 2 __syncthreads per K-step, ~24 KB LDS -> 4-6 blocks/CU.
// Cross-block wave overlap (m114) provides the pipelining.
//
// A staged as FP32 via global_load_lds (16 KB), converted to bf16 at frag-read
// (4 cvt_pk per frag). B staged as bf16 from W1t (8 KB).
//
// LDS swizzles (both verified-0-conflict pattern: 16B-chunk ^ row bits):
//  A (f32 [128][32], 128B rows): chunk j_stored = j ^ (row&7)
//    frag read: lane(row=lane&15, j=(lane>>4)*2+c) -> 16 rows hit each
//    bank-column exactly 2x (2-way, free).
//  B (bf16 [128][32], row-pairs in 128B): chunk j_stored = j' ^ (srow&7),
//    j' = (row&1)*4 + k8, srow = row>>1 (same scheme as R2/R4, measured 0).
// Staging writes LDS linearly; the global source applies the inverse map.
__global__ __launch_bounds__(256, 4) void gemm_score_kernel(
    const float* __restrict__ X,              // [MROWS][DIM] fp32
    const unsigned short* __restrict__ W1t,   // [DIM][DIM]  (e-major)
    const float* __restrict__ b1,
    const float* __restrict__ w2,
    float* __restrict__ scores) {             // [MROWS]
  __shared__ __align__(16) char lds[24576];   // A f32: [0,16K)  B bf16: [16K,24K)

  const int tid = threadIdx.x;
  const int lane = tid & 63;
  const int w = tid >> 6;                     // wave 0..3
  const int wr = w >> 1, wc = w & 1;          // 2x2 wave grid, 64x64 each

  // XCD-chunked swizzle: 4096 blocks, 8 XCDs (hw: xcd = bx%8).
  // swz = (bx&7)*512 + (bx>>3): XCD c covers m-tiles [c*64,(c+1)*64), all 8 n.
  const int bx = blockIdx.x;
  const int swz = (bx & 7) * 512 + (bx >> 3);
  const int m0 = (swz >> 3) * 128;
  const int n0 = (swz & 7) * 128;

  // ---- A staging: 4 gloads/thread; chunk sc = i*256+tid (16B f32 chunks)
  const float* aSrc[4];
#pragma unroll
  for (int i = 0; i < 4; i++) {
    int sc = i * 256 + tid;
    int row = sc >> 3;
    int j = (sc & 7) ^ (row & 7);
    aSrc[i] = X + (size_t)(m0 + row) * DIM + j * 4;
  }
  // ---- B staging: 2 gloads/thread; chunk sc = i*256+tid (16B bf16 chunks)
  const unsigned short* bSrc[2];
#pragma unroll
  for (int i = 0; i < 2; i++) {
    int sc = i * 256 + tid;
    int srow = sc >> 3;
    int j = (sc & 7) ^ (srow & 7);
    int row = srow * 2 + (j >> 2);
    bSrc[i] = W1t + (size_t)(n0 + row) * DIM + (j & 3) * 8;
  }

  // ---- fragment LDS byte offsets
  int aOffs[4][2];
#pragma unroll
  for (int mi = 0; mi < 4; mi++) {
    int row = wr * 64 + mi * 16 + (lane & 15);
#pragma unroll
    for (int c = 0; c < 2; c++) {
      int j = ((lane >> 4) * 2 + c) ^ (row & 7);
      aOffs[mi][c] = row * 128 + j * 16;
    }
  }
  int bOffs[4];
#pragma unroll
  for (int ni = 0; ni < 4; ni++) {
    int row = wc * 64 + ni * 16 + (lane & 15);
    int srow = row >> 1;
    int j = ((row & 1) * 4 + (lane >> 4)) ^ (srow & 7);
    bOffs[ni] = 16384 + srow * 128 + j * 16;
  }

  f32x4 acc[4][4];
#pragma unroll
  for (int mi = 0; mi < 4; mi++)
#pragma unroll
    for (int ni = 0; ni < 4; ni++)
      acc[mi][ni] = (f32x4){0.f, 0.f, 0.f, 0.f};

  for (int kt = 0; kt < 32; ++kt) {
    const int ko = kt * 32;
    // stage A (fp32) + B (bf16); LDS dest is wave-uniform base + lane*16
    gload_lds16(aSrc[0] + ko, lds + w * 1024);
    gload_lds16(aSrc[1] + ko, lds + 4096 + w * 1024);
    gload_lds16(aSrc[2] + ko, lds + 8192 + w * 1024);
    gload_lds16(aSrc[3] + ko, lds + 12288 + w * 1024);
    gload_lds16(bSrc[0] + ko, lds + 16384 + w * 1024);
    gload_lds16(bSrc[1] + ko, lds + 16384 + 4096 + w * 1024);
    __syncthreads();            // drains vmcnt -> staged data visible

    short8 af[4], bfv[4];
#pragma unroll
    for (int mi = 0; mi < 4; mi++) {
      f32x4 lo = *(const f32x4*)(lds + aOffs[mi][0]);
      f32x4 hi = *(const f32x4*)(lds + aOffs[mi][1]);
      af[mi] = cvt8(lo, hi);
    }
#pragma unroll
    for (int ni = 0; ni < 4; ni++)
      bfv[ni] = *(const short8*)(lds + bOffs[ni]);

    __builtin_amdgcn_s_setprio(1);
#pragma unroll
    for (int mi = 0; mi < 4; mi++)
#pragma unroll
      for (int ni = 0; ni < 4; ni++)
        acc[mi][ni] = mfma_bf16(af[mi], bfv[ni], acc[mi][ni]);
    __builtin_amdgcn_s_setprio(0);
    __syncthreads();            // all frag reads consumed -> safe to restage
  }

  // epilogue: scores[row] += sum over this wave's 64 cols of tanh(c + b1) * w2
  const int cg = lane >> 4;   // row group: rows cg*4 + j
  const int cl = lane & 15;   // col within fragment
#pragma unroll
  for (int mi = 0; mi < 4; mi++) {
    float p0 = 0.f, p1 = 0.f, p2 = 0.f, p3 = 0.f;
#pragma unroll
    for (int ni = 0; ni < 4; ni++) {
      int col = n0 + wc * 64 + ni * 16 + cl;
      float w2v = w2[col];
      float b1v = b1[col];
      p0 += fast_tanh(acc[mi][ni][0] + b1v) * w2v;
      p1 += fast_tanh(acc[mi][ni][1] + b1v) * w2v;
      p2 += fast_tanh(acc[mi][ni][2] + b1v) * w2v;
      p3 += fast_tanh(acc[mi][ni][3] + b1v) * w2v;
    }
#pragma unroll
    for (int off = 1; off < 16; off <<= 1) {
      p0 += __shfl_xor(p0, off);
      p1 += __shfl_xor(p1, off);
      p2 += __shfl_xor(p2, off);
      p3 += __shfl_xor(p3, off);
    }
    if (cl == 0) {
      int row = m0 + wr * 64 + mi * 16 + cg * 4;
      atomicAdd(&scores[row + 0], p0);
      atomicAdd(&scores[row + 1], p1);
      atomicAdd(&scores[row + 2], p2);
      atomicAdd(&scores[row + 3], p3);
    }
  }
}

// ---------- kernel 3: masked softmax + u_att + u_last (fp32 X) ----------
__global__ __launch_bounds__(256) void attn_uatt_kernel(
    const float* __restrict__ X,
    const float* __restrict__ scores,
    const int* __restrict__ mask,
    float* __restrict__ u_att,
    float* __restrict__ u_last) {
  const int b = blockIdx.x;
  const int half = blockIdx.y;            // d-range [half*512, half*512+512)
  const int tid = threadIdx.x;
  const int lane = tid & 63;
  const int wave = tid >> 6;

  __shared__ float attn[SEQ];
  __shared__ float rbuf[4];
  __shared__ float part[3][64 * 9];       // padded stride 9

  float s0 = scores[(size_t)b * SEQ + tid];
  float s1 = scores[(size_t)b * SEQ + 256 + tid];
  if (mask[(size_t)b * SEQ + tid]) s0 = -1000000000.0f;
  if (mask[(size_t)b * SEQ + 256 + tid]) s1 = -1000000000.0f;

  float mx = fmaxf(s0, s1);
#pragma unroll
  for (int off = 1; off < 64; off <<= 1) mx = fmaxf(mx, __shfl_xor(mx, off));
  if (lane == 0) rbuf[wave] = mx;
  __syncthreads();
  mx = fmaxf(fmaxf(rbuf[0], rbuf[1]), fmaxf(rbuf[2], rbuf[3]));

  float p0 = expf(s0 - mx), p1 = expf(s1 - mx);
  float sm = p0 + p1;
#pragma unroll
  for (int off = 1; off < 64; off <<= 1) sm += __shfl_xor(sm, off);
  __syncthreads();
  if (lane == 0) rbuf[wave] = sm;
  __syncthreads();
  sm = rbuf[0] + rbuf[1] + rbuf[2] + rbuf[3];
  float inv = 1.0f / sm;
  attn[tid] = p0 * inv;
  attn[tid + 256] = p1 * inv;
  __syncthreads();

  // u_last: exact fp32 copy of X[:, 511, :] (this block's 512-d half)
  if (tid < 128) {
    ((f32x4*)u_last)[(size_t)b * 256 + half * 128 + tid] =
        ((const f32x4*)X)[((size_t)b * SEQ + (SEQ - 1)) * 256 + half * 128 + tid];
  }

  // u_att[b][d] = sum_s attn[s] * X[b][s][d]; block covers 512 d (64 groups of 8)
  const int col = tid & 63;            // 8-float group within the half
  const int sh = tid >> 6;             // s-range split: [sh*128, sh*128+128)
  const f32x4* Xp = (const f32x4*)X + (size_t)b * SEQ * 256 + half * 128 + col * 2;
  f32x4 a0 = {0.f, 0.f, 0.f, 0.f}, a1 = {0.f, 0.f, 0.f, 0.f};
  for (int s = sh * 128; s < sh * 128 + 128; s++) {
    float wgt = attn[s];
    a0 += wgt * Xp[(size_t)s * 256];
    a1 += wgt * Xp[(size_t)s * 256 + 1];
  }
  if (sh) {
#pragma unroll
    for (int j = 0; j < 4; j++) part[sh - 1][col * 9 + j] = a0[j];
#pragma unroll
    for (int j = 0; j < 4; j++) part[sh - 1][col * 9 + 4 + j] = a1[j];
  }
  __syncthreads();
  if (sh == 0) {
#pragma unroll
    for (int j = 0; j < 4; j++)
      a0[j] += part[0][col * 9 + j] + part[1][col * 9 + j] + part[2][col * 9 + j];
#pragma unroll
    for (int j = 0; j < 4; j++)
      a1[j] += part[0][col * 9 + 4 + j] + part[1][col * 9 + 4 + j] + part[2][col * 9 + 4 + j];
    f32x4* dst = (f32x4*)(u_att + (size_t)b * DIM + half * 512 + col * 8);
    dst[0] = a0;
    dst[1] = a1;
  }
}

// ---------- launcher ----------
extern "C" void kernel_launch(void* const* d_in, const int* in_sizes, int n_in,
                              void* d_out, int out_size, void* d_ws, size_t ws_size,
                              hipStream_t stream) {
  const float* X    = (const float*)d_in[0];   // [128][512][1024] fp32
  const int*   mask = (const int*)d_in[1];     // [128][512] int32 (bool)
  const float* W1   = (const float*)d_in[2];   // [1024][1024]
  const float* b1   = (const float*)d_in[3];   // [1024]
  const float* w2   = (const float*)d_in[4];   // [1024]

  float* out    = (float*)d_out;
  float* u_last = out;                          // [128][1024]
  float* u_att  = out + BATCH * DIM;            // [128][1024]

  char* ws = (char*)d_ws;
  unsigned short* W1t = (unsigned short*)ws;                        // 2 MB
  float* scores = (float*)(ws + (size_t)DIM * DIM * 2);             // 256 KB

  hipMemsetAsync(scores, 0, MROWS * sizeof(float), stream);
  hipLaunchKernelGGL(w1t_kernel, dim3(256), dim3(256), 0, stream, W1, W1t);
  hipLaunchKernelGGL(gemm_score_kernel, dim3(4096), dim3(256), 0, stream,
                     X, W1t, b1, w2, scores);
  hipLaunchKernelGGL(attn_uatt_kernel, dim3(128, 2), dim3(256), 0, stream,
                     X, scores, mask, u_att, u_last);
}